// Round 1
// baseline (191.732 us; speedup 1.0000x reference)
//
#include <hip/hip_runtime.h>
#include <hip/hip_bf16.h>

#define BB 16
#define NN 1024
#define DIN 64
#define KK 8
#define DP 64

typedef __bf16 bf16x8 __attribute__((ext_vector_type(8)));
typedef float f32x16 __attribute__((ext_vector_type(16)));

struct bf4 { __hip_bfloat16 a, b, c, d; };

// ---------------------------------------------------------------------------
// Kernel 1: z[k][b][n][e] = relu(sum_d x[b][n][d] * W[k][d][e] + bias[k][e])
// stored as bf16. Grid = K*B*8 blocks (each block: one (k,b), 128 rows).
// ---------------------------------------------------------------------------
__global__ __launch_bounds__(256) void enc_kernel(const float* __restrict__ x,
                                                  const float* __restrict__ W,
                                                  const float* __restrict__ bias,
                                                  __hip_bfloat16* __restrict__ z)
{
    __shared__ float Wl[DIN * DP];   // 16 KB, [d][e]
    __shared__ float xl[16 * 65];    // 16 rows, padded stride 65

    const int bid   = blockIdx.x;        // ((k*BB + b)*8 + chunk)
    const int chunk = bid & 7;
    const int kb    = bid >> 3;
    const int b     = kb & (BB - 1);
    const int k     = kb >> 4;
    const int tid   = threadIdx.x;

    // stage W[k] (4096 floats)
    {
        const float4* src = (const float4*)(W + (size_t)k * DIN * DP);
        float4* dst = (float4*)Wl;
        #pragma unroll
        for (int i = 0; i < 4; ++i) dst[tid + i * 256] = src[tid + i * 256];
    }

    const int lane = tid & 63;
    const int wid  = tid >> 6;
    const int g    = lane >> 4;           // row-subgroup 0..3
    const int e0   = (lane & 15) * 4;     // this lane's 4 output columns
    const int row_loc = wid * 4 + g;      // 0..15

    const float4 bias4 = *(const float4*)(bias + k * DP + e0);

    const int r0 = chunk * 128;
    const float* xb = x + (size_t)b * NN * DIN;

    for (int iter = 0; iter < 8; ++iter) {
        __syncthreads();
        // stage 16 rows of x (1024 floats = 256 float4, one per thread)
        {
            float4 v = ((const float4*)(xb + (size_t)(r0 + iter * 16) * DIN))[tid];
            int row = tid >> 4;      // 16 float4 per row
            int c4  = tid & 15;
            float* d = &xl[row * 65 + c4 * 4];
            d[0] = v.x; d[1] = v.y; d[2] = v.z; d[3] = v.w;
        }
        __syncthreads();

        const float* xr = &xl[row_loc * 65];
        float4 acc = bias4;
        #pragma unroll
        for (int d = 0; d < DIN; ++d) {
            float xv = xr[d];
            float4 w4 = *(const float4*)&Wl[d * DP + e0];
            acc.x += xv * w4.x;
            acc.y += xv * w4.y;
            acc.z += xv * w4.z;
            acc.w += xv * w4.w;
        }

        int row = r0 + iter * 16 + row_loc;
        __hip_bfloat16* zp = z + (((size_t)(k * BB + b)) * NN + row) * DP + e0;
        bf4 v;
        v.a = __float2bfloat16(fmaxf(acc.x, 0.0f));
        v.b = __float2bfloat16(fmaxf(acc.y, 0.0f));
        v.c = __float2bfloat16(fmaxf(acc.z, 0.0f));
        v.d = __float2bfloat16(fmaxf(acc.w, 0.0f));
        *(bf4*)zp = v;
    }
}

// ---------------------------------------------------------------------------
// Kernel 2: R[b][n][m][k] = sum_e z[k][b][n][e] * z[k][b][m][e]
// Grid = B*(N/32)*(N/32) blocks, 256 threads (4 waves).
// Wave w computes attributes k = 2w, 2w+1 via mfma_f32_32x32x16_bf16 (K-dim 64).
// Gram symmetry: A and B fragments are both loaded as "8 consecutive e of a z
// row" — any intra-lane k-permutation in the HW A/B layout cancels since it is
// applied identically to both operands. C/D layout is the m74/m101-verified
// col=lane&31, row=(reg&3)+8*(reg>>2)+4*(lane>>5).
// ---------------------------------------------------------------------------
__global__ __launch_bounds__(256) void gram_kernel(const __hip_bfloat16* __restrict__ z,
                                                   float* __restrict__ out)
{
    __shared__ float tile[32 * 32 * 9];  // k padded 8->9: conflict-free stride

    const int bid = blockIdx.x;
    const int mt  = bid & 31;
    const int nt  = (bid >> 5) & 31;
    const int b   = bid >> 10;
    const int tid  = threadIdx.x;
    const int lane = tid & 63;
    const int wid  = tid >> 6;
    const int k0   = wid * 2;

    const int rrow = lane & 31;   // row within 32-tile (A: n, B: m)
    const int h    = lane >> 5;   // K-half selector

    const size_t kslice = (size_t)BB * NN * DP;
    const size_t baseA0 = (((size_t)(k0 * BB) + b) * NN + nt * 32 + rrow) * DP + h * 8;
    const size_t baseB0 = (((size_t)(k0 * BB) + b) * NN + mt * 32 + rrow) * DP + h * 8;
    const size_t baseA1 = baseA0 + kslice;
    const size_t baseB1 = baseB0 + kslice;

    f32x16 acc0, acc1;
    #pragma unroll
    for (int i = 0; i < 16; ++i) { acc0[i] = 0.0f; acc1[i] = 0.0f; }

    #pragma unroll
    for (int kk = 0; kk < 4; ++kk) {
        bf16x8 a0 = *(const bf16x8*)(z + baseA0 + kk * 16);
        bf16x8 b0 = *(const bf16x8*)(z + baseB0 + kk * 16);
        bf16x8 a1 = *(const bf16x8*)(z + baseA1 + kk * 16);
        bf16x8 b1 = *(const bf16x8*)(z + baseB1 + kk * 16);
        acc0 = __builtin_amdgcn_mfma_f32_32x32x16_bf16(a0, b0, acc0, 0, 0, 0);
        acc1 = __builtin_amdgcn_mfma_f32_32x32x16_bf16(a1, b1, acc1, 0, 0, 0);
    }

    // scatter into LDS tile [n][m][k(pad 9)]
    #pragma unroll
    for (int r = 0; r < 16; ++r) {
        int n = (r & 3) + 8 * (r >> 2) + 4 * h;
        int off = (n * 32 + rrow) * 9;
        tile[off + k0]     = acc0[r];
        tile[off + k0 + 1] = acc1[r];
    }
    __syncthreads();

    // coalesced write-out: per output row n, 32 m * 8 k = 256 contiguous floats
    float* op = out + (((size_t)b * NN + nt * 32) * NN + (size_t)mt * 32) * KK;
    #pragma unroll
    for (int j = 0; j < 8; ++j) {
        int flat = j * 256 + tid;     // float4 index within the 32x32x8 tile
        int n  = flat >> 6;           // 64 float4 per row
        int c4 = flat & 63;           // c4*4 = m*8 + kq
        int m  = c4 >> 1;
        int kq = (c4 & 1) * 4;
        int off = (n * 32 + m) * 9 + kq;
        float4 v = make_float4(tile[off], tile[off + 1], tile[off + 2], tile[off + 3]);
        *(float4*)(op + (size_t)n * NN * KK + c4 * 4) = v;
    }
}

// ---------------------------------------------------------------------------
extern "C" void kernel_launch(void* const* d_in, const int* in_sizes, int n_in,
                              void* d_out, int out_size, void* d_ws, size_t ws_size,
                              hipStream_t stream)
{
    const float* x    = (const float*)d_in[0];
    const float* W    = (const float*)d_in[1];
    const float* bias = (const float*)d_in[2];
    float* out        = (float*)d_out;
    __hip_bfloat16* z = (__hip_bfloat16*)d_ws;   // 8*16*1024*64*2 = 16.8 MB

    enc_kernel<<<dim3(KK * BB * 8), dim3(256), 0, stream>>>(x, W, bias, z);
    gram_kernel<<<dim3(BB * 32 * 32), dim3(256), 0, stream>>>(z, out);
}